// Round 10
// baseline (374.084 us; speedup 1.0000x reference)
//
#include <hip/hip_runtime.h>

typedef __attribute__((ext_vector_type(4))) float f32x4;
typedef __attribute__((ext_vector_type(8))) short s16x8;

#define NB 128      // batch
#define NA 100      // atoms (N)
#define KF 32       // INNER
#define NF 33       // F = INNER+1
#define NU 512      // UNITS
#define ND 3        // DEPTH

#define SZ_S0    (NB * NA * KF)
#define SZ_BONDS (NB * NA * NA)

#define REPS_P1  8     // timing probe: p1 repeated -> top-5 visible
#define REPS_P2B 10    // timing probe: p2b repeated -> top-5 visible

__device__ __forceinline__ unsigned short f2bf(float f) {
    unsigned int u = __float_as_uint(f);
    u = (u + 0x7fffu + ((u >> 16) & 1u)) >> 16;      // RNE
    return (unsigned short)u;
}
__device__ __forceinline__ float bf2f(unsigned short h) {
    return __uint_as_float(((unsigned int)h) << 16);
}

// ---------------------------------------------------------------------------
// Phase 1: per (b,i) row: S0[b,i,f] = sum_j x[b,i,j,f] (f<32);
//          attrAll[b,0,i,f] = x[b,i,i,f]; bonds[b,i,j] = x[b,i,j,32]
// PROBE BUILD: body repeated REPS_P1 times (pure function of x -> identical
// writes each rep; deterministic).
// ---------------------------------------------------------------------------
__global__ __launch_bounds__(256) void p1_reduce(const float* __restrict__ x,
    float* __restrict__ S0, float* __restrict__ attrAll, float* __restrict__ bonds)
{
    const int blk = blockIdx.x;            // b*NA + i
    const int b   = blk / NA;
    const int i   = blk % NA;
    const int t   = threadIdx.x;

    __shared__ float lds[NA * NF];         // 13.2 KB
    __shared__ float red[8][KF];

    for (int rep = 0; rep < REPS_P1; ++rep) {
        const float4* row4 = (const float4*)(x + (size_t)blk * (NA * NF));
        float4* lds4 = (float4*)lds;
        for (int idx = t; idx < (NA * NF) / 4; idx += 256) lds4[idx] = row4[idx];
        __syncthreads();

        const int g = t >> 5;                  // 0..7
        const int f = t & 31;
        float p0 = 0.f, p1 = 0.f;
        for (int j = g; j + 8 < NA; j += 16) {
            p0 += lds[j * NF + f];
            p1 += lds[(j + 8) * NF + f];
        }
        if (g < 4) p0 += lds[(96 + g) * NF + f];   // tail rows 96..99
        red[g][f] = p0 + p1;
        __syncthreads();

        if (t < KF) {
            float s = 0.f;
#pragma unroll
            for (int gg = 0; gg < 8; ++gg) s += red[gg][t];
            S0[(size_t)blk * KF + t] = s;
        } else if (t >= 64 && t < 64 + KF) {
            attrAll[(size_t)b * (ND + 1) * NA * KF + (size_t)i * KF + (t - 64)] = lds[i * NF + (t - 64)];
        } else if (t >= 128 && t < 128 + NA) {
            const int j = t - 128;
            bonds[(size_t)blk * NA + j] = lds[j * NF + KF];
        }
        __syncthreads();   // lds/red reused next rep
    }
}

// ---------------------------------------------------------------------------
// Phase 2a: per-batch recurrence. Produces attrAll[b][d] for d=1..ND.
// ---------------------------------------------------------------------------
__global__ __launch_bounds__(256) void p2a_recur(
    const float* __restrict__ S0, const float* __restrict__ bonds,
    const float* __restrict__ W_inner, const float* __restrict__ b_inner,
    float* __restrict__ attrAll)
{
    __shared__ float S[NA * KF];
    __shared__ float attr[NA * KF];
    __shared__ float Wi[KF * KF];
    __shared__ float rs[NA];

    const int b = blockIdx.x;
    const int t = threadIdx.x;

    const float4* s4 = (const float4*)(S0 + (size_t)b * NA * KF);
    const float4* a4 = (const float4*)(attrAll + (size_t)b * (ND + 1) * NA * KF);
    for (int idx = t; idx < NA * KF / 4; idx += 256) {
        ((float4*)S)[idx]    = s4[idx];
        ((float4*)attr)[idx] = a4[idx];
    }
    if (t < NA) {
        const float* bb = bonds + (size_t)b * NA * NA + t;
        float c0=0.f,c1=0.f,c2=0.f,c3=0.f,c4=0.f,c5=0.f,c6=0.f,c7=0.f;
        int j = 0;
        for (; j + 8 <= NA; j += 8) {
            c0 += bb[(j+0)*NA]; c1 += bb[(j+1)*NA];
            c2 += bb[(j+2)*NA]; c3 += bb[(j+3)*NA];
            c4 += bb[(j+4)*NA]; c5 += bb[(j+5)*NA];
            c6 += bb[(j+6)*NA]; c7 += bb[(j+7)*NA];
        }
        for (; j < NA; ++j) c0 += bb[j*NA];
        rs[t] = 1.f + (((c0+c1)+(c2+c3))+((c4+c5)+(c6+c7)));
    }
    __syncthreads();

    for (int d = 1; d <= ND; ++d) {
        if (t < KF * KF / 4)
            ((float4*)Wi)[t] = ((const float4*)(W_inner + d * KF * KF))[t];
        __syncthreads();

        float core[13];
#pragma unroll
        for (int it = 0; it < 13; ++it) {
            const int idx = t + it * 256;
            if (idx < NA * KF) {
                const int row = idx >> 5, f = idx & 31;
                float acc = b_inner[d * KF + f];
                const float* Sr = S + row * KF;
#pragma unroll
                for (int k = 0; k < KF; ++k) acc += Sr[k] * Wi[k * KF + f];
                core[it] = acc;
            }
        }
        __syncthreads();
#pragma unroll
        for (int it = 0; it < 13; ++it) {
            const int idx = t + it * 256;
            if (idx < NA * KF) {
                const int row = idx >> 5;
                const float cc  = core[it];
                const float old = attr[idx];
                attr[idx] = cc;
                S[idx] += rs[row] * (cc - old);
                attrAll[(size_t)b * (ND + 1) * NA * KF + (size_t)d * NA * KF + idx] = cc;
            }
        }
        __syncthreads();
    }
}

// ---------------------------------------------------------------------------
// pW: split W_output into bf16 hi/lo in B-fragment layout (verified R6).
// ---------------------------------------------------------------------------
__global__ __launch_bounds__(256) void pW_prep(const float* __restrict__ W_output,
    unsigned short* __restrict__ WBh, unsigned short* __restrict__ WBl)
{
    const int i = blockIdx.x * 256 + threadIdx.x;    // 65536 total
    const int d = i >> 14, rem = i & 16383, k = rem >> 9, col = rem & 511;
    const float v = W_output[(size_t)d * (KF * NU) + (size_t)k * NU + col];
    const unsigned short hi = f2bf(v);
    const unsigned short lo = f2bf(v - bf2f(hi));
    const int dst = d * 16384 + (col >> 4) * 512 + (k >> 3) * 128 + (col & 15) * 8 + (k & 7);
    WBh[dst] = hi;
    WBl[dst] = lo;
}

// ---------------------------------------------------------------------------
// Phase 2b (MFMA, 3-sweep common-max softmax): block = (b,d), 448 thr = 7 waves.
// Wave w: rows w*16..w*16+15, all 512 cols.
//  Sweep A: logits -> fmax only (no exp). Merge max (fmax, exp-free).
//  Sweep B: 1 exp/logit, accumulate s. Merge s = pure add (common max).
//  Sweep C: 1 exp/logit, f += e*inv, cross-wave reduce.
// PROBE BUILD: body repeated REPS_P2B times, deterministic.
// ---------------------------------------------------------------------------
__global__ __launch_bounds__(448) void p2b_mfma(
    const float* __restrict__ attrAll,
    const unsigned short* __restrict__ WBh_g, const unsigned short* __restrict__ WBl_g,
    const float* __restrict__ b_output, float* __restrict__ fpPart)
{
    extern __shared__ unsigned char smraw[];
    unsigned short* WBh  = (unsigned short*)smraw;        // 32768 B
    unsigned short* WBl  = WBh + 16384;                   // 32768 B
    unsigned short* aAh  = WBl + 16384;                   //  7168 B
    unsigned short* aAl  = aAh + 3584;                    //  7168 B
    float*          biasL= (float*)(aAl + 3584);          //  2048 B (total 80 KB)
    float*          fpw  = (float*)aAh;                   // overlay after frag loads

    const int blk = blockIdx.x;
    const int b   = blk & (NB - 1);
    const int d   = blk >> 7;
    const int t   = threadIdx.x;
    const int l   = t & 63;
    const int w   = t >> 6;                               // 0..6

    for (int rep = 0; rep < REPS_P2B; ++rep) {
        // stage W hi/lo (coalesced), bias
        for (int i = t; i < 2048; i += 448) ((float4*)WBh)[i] = ((const float4*)WBh_g)[d * 2048 + i];
        for (int i = t; i < 2048; i += 448) ((float4*)WBl)[i] = ((const float4*)WBl_g)[d * 2048 + i];
        for (int i = t; i < NU; i += 448)   biasL[i] = b_output[d * NU + i];

        // stage attr -> bf16 hi/lo in A-fragment layout (112 rows x 32 k)
        const float* A = attrAll + ((size_t)b * (ND + 1) + d) * (NA * KF);
        for (int i = t; i < 3584; i += 448) {
            const int gr = i >> 5, k = i & 31;
            const float v = (gr < NA) ? A[gr * KF + k] : 0.f;
            const unsigned short hi = f2bf(v);
            const unsigned short lo = f2bf(v - bf2f(hi));
            const int dst = ((gr >> 4) * 4 + (k >> 3)) * 128 + (gr & 15) * 8 + (k & 7);
            aAh[dst] = hi;
            aAl[dst] = lo;
        }
        __syncthreads();

        // A-fragments for this wave's row-tile
        const int aoff = (w * 4 + (l >> 4)) * 128 + (l & 15) * 8;
        const s16x8 ah = *(const s16x8*)&aAh[aoff];
        const s16x8 al = *(const s16x8*)&aAl[aoff];
        __syncthreads();   // aAh/aAl dead; fpw may overwrite after sweeps

        // ---- sweep A: row max (no exp) --------------------------------------
        float m[4] = {-1e30f, -1e30f, -1e30f, -1e30f};
#pragma unroll 2
        for (int tt = 0; tt < 32; ++tt) {
            const int boff = tt * 512 + (l >> 4) * 128 + (l & 15) * 8;
            const s16x8 bh = *(const s16x8*)&WBh[boff];
            const s16x8 bl = *(const s16x8*)&WBl[boff];
            f32x4 c = {0.f, 0.f, 0.f, 0.f};
            c = __builtin_amdgcn_mfma_f32_16x16x32_bf16(ah, bh, c, 0, 0, 0);
            c = __builtin_amdgcn_mfma_f32_16x16x32_bf16(ah, bl, c, 0, 0, 0);
            c = __builtin_amdgcn_mfma_f32_16x16x32_bf16(al, bh, c, 0, 0, 0);
            const float bias = biasL[tt * 16 + (l & 15)];
#pragma unroll
            for (int r = 0; r < 4; ++r) m[r] = fmaxf(m[r], c[r] + bias);
        }
        // merge max across the 16 col-lanes (exp-free)
#pragma unroll
        for (int off = 1; off <= 8; off <<= 1)
#pragma unroll
            for (int r = 0; r < 4; ++r) m[r] = fmaxf(m[r], __shfl_xor(m[r], off, 64));

        // ---- sweep B: e-sum with common max ---------------------------------
        float s[4] = {0.f, 0.f, 0.f, 0.f};
#pragma unroll 2
        for (int tt = 0; tt < 32; ++tt) {
            const int boff = tt * 512 + (l >> 4) * 128 + (l & 15) * 8;
            const s16x8 bh = *(const s16x8*)&WBh[boff];
            const s16x8 bl = *(const s16x8*)&WBl[boff];
            f32x4 c = {0.f, 0.f, 0.f, 0.f};
            c = __builtin_amdgcn_mfma_f32_16x16x32_bf16(ah, bh, c, 0, 0, 0);
            c = __builtin_amdgcn_mfma_f32_16x16x32_bf16(ah, bl, c, 0, 0, 0);
            c = __builtin_amdgcn_mfma_f32_16x16x32_bf16(al, bh, c, 0, 0, 0);
            const float bias = biasL[tt * 16 + (l & 15)];
#pragma unroll
            for (int r = 0; r < 4; ++r) s[r] += __expf(c[r] + bias - m[r]);
        }
        // merge s = pure adds (common max)
#pragma unroll
        for (int off = 1; off <= 8; off <<= 1)
#pragma unroll
            for (int r = 0; r < 4; ++r) s[r] += __shfl_xor(s[r], off, 64);

        float inv[4];
#pragma unroll
        for (int r = 0; r < 4; ++r) {
            const int grow = w * 16 + (l >> 4) * 4 + r;
            inv[r] = (grow < NA) ? 1.f / s[r] : 0.f;      // mask pad rows
        }

        // ---- sweep C: fp accumulation ----------------------------------------
#pragma unroll 2
        for (int tt = 0; tt < 32; ++tt) {
            const int boff = tt * 512 + (l >> 4) * 128 + (l & 15) * 8;
            const s16x8 bh = *(const s16x8*)&WBh[boff];
            const s16x8 bl = *(const s16x8*)&WBl[boff];
            f32x4 c = {0.f, 0.f, 0.f, 0.f};
            c = __builtin_amdgcn_mfma_f32_16x16x32_bf16(ah, bh, c, 0, 0, 0);
            c = __builtin_amdgcn_mfma_f32_16x16x32_bf16(ah, bl, c, 0, 0, 0);
            c = __builtin_amdgcn_mfma_f32_16x16x32_bf16(al, bh, c, 0, 0, 0);
            const float bias = biasL[tt * 16 + (l & 15)];
            float f = 0.f;
#pragma unroll
            for (int r = 0; r < 4; ++r)
                f += __expf(c[r] + bias - m[r]) * inv[r];
            f += __shfl_xor(f, 16, 64);
            f += __shfl_xor(f, 32, 64);
            if (l < 16) fpw[w * NU + tt * 16 + l] = f;
        }
        __syncthreads();

        for (int u = t; u < NU; u += 448) {
            float sacc = 0.f;
#pragma unroll
            for (int ww = 0; ww < 7; ++ww) sacc += fpw[ww * NU + u];
            fpPart[((size_t)d * NB + b) * NU + u] = sacc;
        }
        __syncthreads();   // fpw reads done before next rep restages
    }
}

// ---------------------------------------------------------------------------
// Phase 2c: out[b][u] = sum_d fpPart[d][b][u]
// ---------------------------------------------------------------------------
__global__ __launch_bounds__(512) void p2c_out(const float* __restrict__ fpPart,
                                               float* __restrict__ out)
{
    const int b = blockIdx.x, t = threadIdx.x;
    float s = 0.f;
#pragma unroll
    for (int d = 0; d <= ND; ++d) s += fpPart[((size_t)d * NB + b) * NU + t];
    out[(size_t)b * NU + t] = s;
}

// ---------------------------------------------------------------------------
extern "C" void kernel_launch(void* const* d_in, const int* in_sizes, int n_in,
                              void* d_out, int out_size, void* d_ws, size_t ws_size,
                              hipStream_t stream) {
    (void)in_sizes; (void)n_in; (void)out_size; (void)ws_size;
    const float* x        = (const float*)d_in[0];
    const float* W_inner  = (const float*)d_in[1];
    const float* b_inner  = (const float*)d_in[2];
    const float* W_output = (const float*)d_in[3];
    const float* b_output = (const float*)d_in[4];
    float* out = (float*)d_out;

    float* S0      = (float*)d_ws;
    float* bonds   = S0 + SZ_S0;
    float* attrAll = bonds + SZ_BONDS;
    float* fpPart  = bonds;                       // overlay: bonds dead after p2a
    unsigned short* WBh = (unsigned short*)S0;    // overlay: S0 dead after p2a
    unsigned short* WBl = WBh + 65536;

    p1_reduce<<<NB * NA, 256, 0, stream>>>(x, S0, attrAll, bonds);
    p2a_recur<<<NB, 256, 0, stream>>>(S0, bonds, W_inner, b_inner, attrAll);
    pW_prep<<<256, 256, 0, stream>>>(W_output, WBh, WBl);

    const size_t smemB = 81920;                   // 80 KB
    hipFuncSetAttribute(reinterpret_cast<const void*>(p2b_mfma),
                        hipFuncAttributeMaxDynamicSharedMemorySize, (int)smemB);
    p2b_mfma<<<NB * (ND + 1), 448, smemB, stream>>>(attrAll, WBh, WBl, b_output, fpPart);
    p2c_out<<<NB, 512, 0, stream>>>(fpPart, out);
}

// Round 11
// 73.343 us; speedup vs baseline: 5.1004x; 5.1004x over previous
//
#include <hip/hip_runtime.h>

typedef __attribute__((ext_vector_type(4))) float f32x4;
typedef __attribute__((ext_vector_type(8))) short s16x8;

#define NB 128      // batch
#define NA 100      // atoms (N)
#define KF 32       // INNER
#define NF 33       // F = INNER+1
#define NU 512      // UNITS
#define ND 3        // DEPTH

#define SZ_S0    (NB * NA * KF)
#define SZ_BONDS (NB * NA * NA)

__device__ __forceinline__ unsigned short f2bf(float f) {
    unsigned int u = __float_as_uint(f);
    u = (u + 0x7fffu + ((u >> 16) & 1u)) >> 16;      // RNE
    return (unsigned short)u;
}
__device__ __forceinline__ float bf2f(unsigned short h) {
    return __uint_as_float(((unsigned int)h) << 16);
}

// ---------------------------------------------------------------------------
// Phase 1: per (b,i) row: S0[b,i,f] = sum_j x[b,i,j,f] (f<32);
//          attrAll[b,0,i,f] = x[b,i,i,f]; bonds[b,i,j] = x[b,i,j,32]
// ---------------------------------------------------------------------------
__global__ __launch_bounds__(256) void p1_reduce(const float* __restrict__ x,
    float* __restrict__ S0, float* __restrict__ attrAll, float* __restrict__ bonds)
{
    const int blk = blockIdx.x;            // b*NA + i
    const int b   = blk / NA;
    const int i   = blk % NA;
    const int t   = threadIdx.x;

    __shared__ float lds[NA * NF];         // 13.2 KB
    __shared__ float red[8][KF];

    const float4* row4 = (const float4*)(x + (size_t)blk * (NA * NF));
    float4* lds4 = (float4*)lds;
    for (int idx = t; idx < (NA * NF) / 4; idx += 256) lds4[idx] = row4[idx];
    __syncthreads();

    const int g = t >> 5;                  // 0..7
    const int f = t & 31;
    float p0 = 0.f, p1 = 0.f;
    for (int j = g; j + 8 < NA; j += 16) {
        p0 += lds[j * NF + f];
        p1 += lds[(j + 8) * NF + f];
    }
    if (g < 4) p0 += lds[(96 + g) * NF + f];   // tail rows 96..99
    red[g][f] = p0 + p1;
    __syncthreads();

    if (t < KF) {
        float s = 0.f;
#pragma unroll
        for (int gg = 0; gg < 8; ++gg) s += red[gg][t];
        S0[(size_t)blk * KF + t] = s;
    } else if (t >= 64 && t < 64 + KF) {
        attrAll[(size_t)b * (ND + 1) * NA * KF + (size_t)i * KF + (t - 64)] = lds[i * NF + (t - 64)];
    } else if (t >= 128 && t < 128 + NA) {
        const int j = t - 128;
        bonds[(size_t)blk * NA + j] = lds[j * NF + KF];
    }
}

// ---------------------------------------------------------------------------
// Phase 2a v2: rows of the recurrence are independent -> block = (b, half).
// 256 blocks (all CUs). Per thread: f = t&31 fixed; W-column in 32 VGPRs
// (global, L2-hot, loaded once per depth); Sr reads are broadcast b128.
// ---------------------------------------------------------------------------
#define NAH 50                        // rows per half-block
#define ELH (NAH * KF)                // 1600 elements per half
__global__ __launch_bounds__(256) void p2a_recur(
    const float* __restrict__ S0, const float* __restrict__ bonds,
    const float* __restrict__ W_inner, const float* __restrict__ b_inner,
    float* __restrict__ attrAll)
{
    __shared__ float S[ELH];          // 6.4 KB
    __shared__ float attr[ELH];
    __shared__ float rs[NAH];

    const int blk  = blockIdx.x;
    const int half = blk & 1;
    const int b    = blk >> 1;
    const int t    = threadIdx.x;
    const int f    = t & 31;

    const float4* s4 = (const float4*)(S0 + (size_t)b * NA * KF + half * ELH);
    const float4* a4 = (const float4*)(attrAll + (size_t)b * (ND + 1) * NA * KF + half * ELH);
    for (int idx = t; idx < ELH / 4; idx += 256) {
        ((float4*)S)[idx]    = s4[idx];
        ((float4*)attr)[idx] = a4[idx];
    }
    if (t < NAH) {
        const int i = half * NAH + t;             // global row
        const float* bb = bonds + (size_t)b * NA * NA + i;
        float c0=0.f,c1=0.f,c2=0.f,c3=0.f,c4=0.f,c5=0.f,c6=0.f,c7=0.f;
        int j = 0;
        for (; j + 8 <= NA; j += 8) {
            c0 += bb[(j+0)*NA]; c1 += bb[(j+1)*NA];
            c2 += bb[(j+2)*NA]; c3 += bb[(j+3)*NA];
            c4 += bb[(j+4)*NA]; c5 += bb[(j+5)*NA];
            c6 += bb[(j+6)*NA]; c7 += bb[(j+7)*NA];
        }
        for (; j < NA; ++j) c0 += bb[j*NA];
        rs[t] = 1.f + (((c0+c1)+(c2+c3))+((c4+c5)+(c6+c7)));
    }
    __syncthreads();

    float* attrDst = attrAll + (size_t)b * (ND + 1) * NA * KF + half * ELH;

    for (int d = 1; d <= ND; ++d) {
        // W column f into registers (coalesced global, L2-hot)
        float Wc[KF];
        const float* Wd = W_inner + d * KF * KF + f;
#pragma unroll
        for (int k = 0; k < KF; ++k) Wc[k] = Wd[k * KF];
        const float bi = b_inner[d * KF + f];

        float core[7];
#pragma unroll
        for (int it = 0; it < 7; ++it) {
            const int idx = t + it * 256;
            if (idx < ELH) {
                const int row = idx >> 5;
                const float4* Sr4 = (const float4*)(S + row * KF);   // broadcast b128
                float acc = bi;
#pragma unroll
                for (int q = 0; q < 8; ++q) {
                    const float4 sv = Sr4[q];
                    acc += sv.x * Wc[4*q] + sv.y * Wc[4*q+1]
                         + sv.z * Wc[4*q+2] + sv.w * Wc[4*q+3];
                }
                core[it] = acc;
            }
        }
        __syncthreads();
#pragma unroll
        for (int it = 0; it < 7; ++it) {
            const int idx = t + it * 256;
            if (idx < ELH) {
                const int row = idx >> 5;
                const float cc  = core[it];
                const float old = attr[idx];
                attr[idx] = cc;
                S[idx] += rs[row] * (cc - old);
                attrDst[(size_t)d * NA * KF + idx] = cc;
            }
        }
        __syncthreads();
    }
}

// ---------------------------------------------------------------------------
// pW: split W_output into bf16 hi/lo in B-fragment layout (verified R6).
// ---------------------------------------------------------------------------
__global__ __launch_bounds__(256) void pW_prep(const float* __restrict__ W_output,
    unsigned short* __restrict__ WBh, unsigned short* __restrict__ WBl)
{
    const int i = blockIdx.x * 256 + threadIdx.x;    // 65536 total
    const int d = i >> 14, rem = i & 16383, k = rem >> 9, col = rem & 511;
    const float v = W_output[(size_t)d * (KF * NU) + (size_t)k * NU + col];
    const unsigned short hi = f2bf(v);
    const unsigned short lo = f2bf(v - bf2f(hi));
    const int dst = d * 16384 + (col >> 4) * 512 + (k >> 3) * 128 + (col & 15) * 8 + (k & 7);
    WBh[dst] = hi;
    WBl[dst] = lo;
}

// ---------------------------------------------------------------------------
// Phase 2b (MFMA, 3-sweep): block = (b,d), 448 thr = 7 waves.
//  Sweep A: hi-only MFMA row max (error <~1.2, safe as common shift).
//  Sweep B: full 3-MFMA logits, s += exp(c-m); merge = pure adds.
//           K[r] = m[r] + log2(s[r])/log2(e)  (i.e. m + ln s), pad rows -> 1e30.
//  Sweep C: f += exp(c - K)   (no mul by inv).
// ---------------------------------------------------------------------------
__global__ __launch_bounds__(448) void p2b_mfma(
    const float* __restrict__ attrAll,
    const unsigned short* __restrict__ WBh_g, const unsigned short* __restrict__ WBl_g,
    const float* __restrict__ b_output, float* __restrict__ fpPart)
{
    extern __shared__ unsigned char smraw[];
    unsigned short* WBh  = (unsigned short*)smraw;        // 32768 B
    unsigned short* WBl  = WBh + 16384;                   // 32768 B
    unsigned short* aAh  = WBl + 16384;                   //  7168 B
    unsigned short* aAl  = aAh + 3584;                    //  7168 B
    float*          biasL= (float*)(aAl + 3584);          //  2048 B (total 80 KB)
    float*          fpw  = (float*)aAh;                   // overlay after frag loads

    const int blk = blockIdx.x;
    const int b   = blk & (NB - 1);
    const int d   = blk >> 7;
    const int t   = threadIdx.x;
    const int l   = t & 63;
    const int w   = t >> 6;                               // 0..6

    // stage W hi/lo (coalesced), bias
    for (int i = t; i < 2048; i += 448) ((float4*)WBh)[i] = ((const float4*)WBh_g)[d * 2048 + i];
    for (int i = t; i < 2048; i += 448) ((float4*)WBl)[i] = ((const float4*)WBl_g)[d * 2048 + i];
    for (int i = t; i < NU; i += 448)   biasL[i] = b_output[d * NU + i];

    // stage attr -> bf16 hi/lo in A-fragment layout (112 rows x 32 k)
    const float* A = attrAll + ((size_t)b * (ND + 1) + d) * (NA * KF);
    for (int i = t; i < 3584; i += 448) {
        const int gr = i >> 5, k = i & 31;
        const float v = (gr < NA) ? A[gr * KF + k] : 0.f;
        const unsigned short hi = f2bf(v);
        const unsigned short lo = f2bf(v - bf2f(hi));
        const int dst = ((gr >> 4) * 4 + (k >> 3)) * 128 + (gr & 15) * 8 + (k & 7);
        aAh[dst] = hi;
        aAl[dst] = lo;
    }
    __syncthreads();

    // A-fragments for this wave's row-tile
    const int aoff = (w * 4 + (l >> 4)) * 128 + (l & 15) * 8;
    const s16x8 ah = *(const s16x8*)&aAh[aoff];
    const s16x8 al = *(const s16x8*)&aAl[aoff];
    __syncthreads();   // aAh/aAl dead; fpw may overwrite after sweeps

    const int laneoff = (l >> 4) * 128 + (l & 15) * 8;

    // ---- sweep A: row max, hi-only MFMA (no exp) ---------------------------
    float m[4] = {-1e30f, -1e30f, -1e30f, -1e30f};
#pragma unroll 2
    for (int tt = 0; tt < 32; ++tt) {
        const s16x8 bh = *(const s16x8*)&WBh[tt * 512 + laneoff];
        f32x4 c = {0.f, 0.f, 0.f, 0.f};
        c = __builtin_amdgcn_mfma_f32_16x16x32_bf16(ah, bh, c, 0, 0, 0);
        const float bias = biasL[tt * 16 + (l & 15)];
#pragma unroll
        for (int r = 0; r < 4; ++r) m[r] = fmaxf(m[r], c[r] + bias);
    }
#pragma unroll
    for (int off = 1; off <= 8; off <<= 1)
#pragma unroll
        for (int r = 0; r < 4; ++r) m[r] = fmaxf(m[r], __shfl_xor(m[r], off, 64));

    // ---- sweep B: e-sum with common max ------------------------------------
    float s[4] = {0.f, 0.f, 0.f, 0.f};
#pragma unroll 2
    for (int tt = 0; tt < 32; ++tt) {
        const s16x8 bh = *(const s16x8*)&WBh[tt * 512 + laneoff];
        const s16x8 bl = *(const s16x8*)&WBl[tt * 512 + laneoff];
        f32x4 c = {0.f, 0.f, 0.f, 0.f};
        c = __builtin_amdgcn_mfma_f32_16x16x32_bf16(ah, bh, c, 0, 0, 0);
        c = __builtin_amdgcn_mfma_f32_16x16x32_bf16(ah, bl, c, 0, 0, 0);
        c = __builtin_amdgcn_mfma_f32_16x16x32_bf16(al, bh, c, 0, 0, 0);
        const float bias = biasL[tt * 16 + (l & 15)];
#pragma unroll
        for (int r = 0; r < 4; ++r) s[r] += __expf(c[r] + bias - m[r]);
    }
#pragma unroll
    for (int off = 1; off <= 8; off <<= 1)
#pragma unroll
        for (int r = 0; r < 4; ++r) s[r] += __shfl_xor(s[r], off, 64);

    float K[4];
#pragma unroll
    for (int r = 0; r < 4; ++r) {
        const int grow = w * 16 + (l >> 4) * 4 + r;
        K[r] = (grow < NA) ? (m[r] + __logf(s[r])) : 1e30f;   // exp(c-K) = e/s
    }

    // ---- sweep C: fp accumulation ------------------------------------------
#pragma unroll 2
    for (int tt = 0; tt < 32; ++tt) {
        const s16x8 bh = *(const s16x8*)&WBh[tt * 512 + laneoff];
        const s16x8 bl = *(const s16x8*)&WBl[tt * 512 + laneoff];
        f32x4 c = {0.f, 0.f, 0.f, 0.f};
        c = __builtin_amdgcn_mfma_f32_16x16x32_bf16(ah, bh, c, 0, 0, 0);
        c = __builtin_amdgcn_mfma_f32_16x16x32_bf16(ah, bl, c, 0, 0, 0);
        c = __builtin_amdgcn_mfma_f32_16x16x32_bf16(al, bh, c, 0, 0, 0);
        const float bias = biasL[tt * 16 + (l & 15)];
        float f = 0.f;
#pragma unroll
        for (int r = 0; r < 4; ++r) f += __expf(c[r] + bias - K[r]);
        f += __shfl_xor(f, 16, 64);
        f += __shfl_xor(f, 32, 64);
        if (l < 16) fpw[w * NU + tt * 16 + l] = f;
    }
    __syncthreads();

    for (int u = t; u < NU; u += 448) {
        float sacc = 0.f;
#pragma unroll
        for (int ww = 0; ww < 7; ++ww) sacc += fpw[ww * NU + u];
        fpPart[((size_t)d * NB + b) * NU + u] = sacc;
    }
}

// ---------------------------------------------------------------------------
// Phase 2c: out[b][u] = sum_d fpPart[d][b][u]
// ---------------------------------------------------------------------------
__global__ __launch_bounds__(512) void p2c_out(const float* __restrict__ fpPart,
                                               float* __restrict__ out)
{
    const int b = blockIdx.x, t = threadIdx.x;
    float s = 0.f;
#pragma unroll
    for (int d = 0; d <= ND; ++d) s += fpPart[((size_t)d * NB + b) * NU + t];
    out[(size_t)b * NU + t] = s;
}

// ---------------------------------------------------------------------------
extern "C" void kernel_launch(void* const* d_in, const int* in_sizes, int n_in,
                              void* d_out, int out_size, void* d_ws, size_t ws_size,
                              hipStream_t stream) {
    (void)in_sizes; (void)n_in; (void)out_size; (void)ws_size;
    const float* x        = (const float*)d_in[0];
    const float* W_inner  = (const float*)d_in[1];
    const float* b_inner  = (const float*)d_in[2];
    const float* W_output = (const float*)d_in[3];
    const float* b_output = (const float*)d_in[4];
    float* out = (float*)d_out;

    float* S0      = (float*)d_ws;
    float* bonds   = S0 + SZ_S0;
    float* attrAll = bonds + SZ_BONDS;
    float* fpPart  = bonds;                       // overlay: bonds dead after p2a
    unsigned short* WBh = (unsigned short*)S0;    // overlay: S0 dead after p2a
    unsigned short* WBl = WBh + 65536;

    p1_reduce<<<NB * NA, 256, 0, stream>>>(x, S0, attrAll, bonds);
    p2a_recur<<<NB * 2, 256, 0, stream>>>(S0, bonds, W_inner, b_inner, attrAll);
    pW_prep<<<256, 256, 0, stream>>>(W_output, WBh, WBl);

    const size_t smemB = 81920;                   // 80 KB
    hipFuncSetAttribute(reinterpret_cast<const void*>(p2b_mfma),
                        hipFuncAttributeMaxDynamicSharedMemorySize, (int)smemB);
    p2b_mfma<<<NB * (ND + 1), 448, smemB, stream>>>(attrAll, WBh, WBl, b_output, fpPart);
    p2c_out<<<NB, 512, 0, stream>>>(fpPart, out);
}

// Round 12
// 69.944 us; speedup vs baseline: 5.3483x; 1.0486x over previous
//
#include <hip/hip_runtime.h>

typedef __attribute__((ext_vector_type(4))) float f32x4;
typedef __attribute__((ext_vector_type(8))) short s16x8;

#define NB 128      // batch
#define NA 100      // atoms (N)
#define KF 32       // INNER
#define NF 33       // F = INNER+1
#define NU 512      // UNITS
#define ND 3        // DEPTH

#define SZ_S0    (NB * NA * KF)
#define SZ_BONDS (NB * NA * NA)

__device__ __forceinline__ unsigned short f2bf(float f) {
    unsigned int u = __float_as_uint(f);
    u = (u + 0x7fffu + ((u >> 16) & 1u)) >> 16;      // RNE
    return (unsigned short)u;
}
__device__ __forceinline__ float bf2f(unsigned short h) {
    return __uint_as_float(((unsigned int)h) << 16);
}
// pack two nonneg f32 into bf16 pair (round-half-up: add 0x8000, trunc)
__device__ __forceinline__ unsigned int pack_bf16(float a, float b) {
    const unsigned int ua = (__float_as_uint(a) + 0x8000u) >> 16;
    const unsigned int ub = (__float_as_uint(b) + 0x8000u) & 0xffff0000u;
    return ua | ub;
}

// ---------------------------------------------------------------------------
// Phase 1: per (b,i) row: S0[b,i,f] = sum_j x[b,i,j,f] (f<32);
//          attrAll[b,0,i,f] = x[b,i,i,f]; bonds[b,i,j] = x[b,i,j,32]
// ---------------------------------------------------------------------------
__global__ __launch_bounds__(256) void p1_reduce(const float* __restrict__ x,
    float* __restrict__ S0, float* __restrict__ attrAll, float* __restrict__ bonds)
{
    const int blk = blockIdx.x;            // b*NA + i
    const int b   = blk / NA;
    const int i   = blk % NA;
    const int t   = threadIdx.x;

    __shared__ float lds[NA * NF];         // 13.2 KB
    __shared__ float red[8][KF];

    const float4* row4 = (const float4*)(x + (size_t)blk * (NA * NF));
    float4* lds4 = (float4*)lds;
    for (int idx = t; idx < (NA * NF) / 4; idx += 256) lds4[idx] = row4[idx];
    __syncthreads();

    const int g = t >> 5;                  // 0..7
    const int f = t & 31;
    float p0 = 0.f, p1 = 0.f;
    for (int j = g; j + 8 < NA; j += 16) {
        p0 += lds[j * NF + f];
        p1 += lds[(j + 8) * NF + f];
    }
    if (g < 4) p0 += lds[(96 + g) * NF + f];   // tail rows 96..99
    red[g][f] = p0 + p1;
    __syncthreads();

    if (t < KF) {
        float s = 0.f;
#pragma unroll
        for (int gg = 0; gg < 8; ++gg) s += red[gg][t];
        S0[(size_t)blk * KF + t] = s;
    } else if (t >= 64 && t < 64 + KF) {
        attrAll[(size_t)b * (ND + 1) * NA * KF + (size_t)i * KF + (t - 64)] = lds[i * NF + (t - 64)];
    } else if (t >= 128 && t < 128 + NA) {
        const int j = t - 128;
        bonds[(size_t)blk * NA + j] = lds[j * NF + KF];
    }
}

// ---------------------------------------------------------------------------
// Phase 2a (+fused pW): blocks 0..255 = recurrence halves (b, half);
// blocks 256..271 = W_output bf16 hi/lo split into B-fragment layout.
// ---------------------------------------------------------------------------
#define NAH 50                        // rows per half-block
#define ELH (NAH * KF)                // 1600 elements per half
__global__ __launch_bounds__(256) void p2a_recur(
    const float* __restrict__ S0, const float* __restrict__ bonds,
    const float* __restrict__ W_inner, const float* __restrict__ b_inner,
    float* __restrict__ attrAll,
    const float* __restrict__ W_output,
    unsigned short* __restrict__ WBh, unsigned short* __restrict__ WBl)
{
    const int blk = blockIdx.x;
    const int t   = threadIdx.x;

    if (blk >= NB * 2) {
        // ---- fused pW slice: 16 blocks x 4096 elements ----
        const int base = (blk - NB * 2) * 4096;
        for (int j = t; j < 4096; j += 256) {
            const int i = base + j;                      // 0..65535
            const int d = i >> 14, rem = i & 16383, k = rem >> 9, col = rem & 511;
            const float v = W_output[(size_t)d * (KF * NU) + (size_t)k * NU + col];
            const unsigned short hi = f2bf(v);
            const unsigned short lo = f2bf(v - bf2f(hi));
            const int dst = d * 16384 + (col >> 4) * 512 + (k >> 3) * 128 + (col & 15) * 8 + (k & 7);
            WBh[dst] = hi;
            WBl[dst] = lo;
        }
        return;
    }

    __shared__ float S[ELH];          // 6.4 KB
    __shared__ float attr[ELH];
    __shared__ float rs[NAH];

    const int half = blk & 1;
    const int b    = blk >> 1;
    const int f    = t & 31;

    const float4* s4 = (const float4*)(S0 + (size_t)b * NA * KF + half * ELH);
    const float4* a4 = (const float4*)(attrAll + (size_t)b * (ND + 1) * NA * KF + half * ELH);
    for (int idx = t; idx < ELH / 4; idx += 256) {
        ((float4*)S)[idx]    = s4[idx];
        ((float4*)attr)[idx] = a4[idx];
    }
    if (t < NAH) {
        const int i = half * NAH + t;             // global row
        const float* bb = bonds + (size_t)b * NA * NA + i;
        float c0=0.f,c1=0.f,c2=0.f,c3=0.f,c4=0.f,c5=0.f,c6=0.f,c7=0.f;
        int j = 0;
        for (; j + 8 <= NA; j += 8) {
            c0 += bb[(j+0)*NA]; c1 += bb[(j+1)*NA];
            c2 += bb[(j+2)*NA]; c3 += bb[(j+3)*NA];
            c4 += bb[(j+4)*NA]; c5 += bb[(j+5)*NA];
            c6 += bb[(j+6)*NA]; c7 += bb[(j+7)*NA];
        }
        for (; j < NA; ++j) c0 += bb[j*NA];
        rs[t] = 1.f + (((c0+c1)+(c2+c3))+((c4+c5)+(c6+c7)));
    }
    __syncthreads();

    float* attrDst = attrAll + (size_t)b * (ND + 1) * NA * KF + half * ELH;

    for (int d = 1; d <= ND; ++d) {
        float Wc[KF];
        const float* Wd = W_inner + d * KF * KF + f;
#pragma unroll
        for (int k = 0; k < KF; ++k) Wc[k] = Wd[k * KF];
        const float bi = b_inner[d * KF + f];

        float core[7];
#pragma unroll
        for (int it = 0; it < 7; ++it) {
            const int idx = t + it * 256;
            if (idx < ELH) {
                const int row = idx >> 5;
                const float4* Sr4 = (const float4*)(S + row * KF);   // broadcast b128
                float acc = bi;
#pragma unroll
                for (int q = 0; q < 8; ++q) {
                    const float4 sv = Sr4[q];
                    acc += sv.x * Wc[4*q] + sv.y * Wc[4*q+1]
                         + sv.z * Wc[4*q+2] + sv.w * Wc[4*q+3];
                }
                core[it] = acc;
            }
        }
        __syncthreads();
#pragma unroll
        for (int it = 0; it < 7; ++it) {
            const int idx = t + it * 256;
            if (idx < ELH) {
                const int row = idx >> 5;
                const float cc  = core[it];
                const float old = attr[idx];
                attr[idx] = cc;
                S[idx] += rs[row] * (cc - old);
                attrDst[(size_t)d * NA * KF + idx] = cc;
            }
        }
        __syncthreads();
    }
}

// ---------------------------------------------------------------------------
// Phase 2b (MFMA, 3-sweep, e-in-registers): block = (b,d), 448 thr = 7 waves.
//  Sweep A: hi-only MFMA row max (error <~1.5, safe common shift).
//  Sweep B: full 3-MFMA logits, e=exp(c-m) packed bf16 into 64 VGPRs; s += e.
//  Sweep C: unpack e, f += e*inv  -- NO MFMA / LDS / exp.
// ---------------------------------------------------------------------------
__global__ __launch_bounds__(448, 4) void p2b_mfma(
    const float* __restrict__ attrAll,
    const unsigned short* __restrict__ WBh_g, const unsigned short* __restrict__ WBl_g,
    const float* __restrict__ b_output, float* __restrict__ fpPart)
{
    extern __shared__ unsigned char smraw[];
    unsigned short* WBh  = (unsigned short*)smraw;        // 32768 B
    unsigned short* WBl  = WBh + 16384;                   // 32768 B
    unsigned short* aAh  = WBl + 16384;                   //  7168 B
    unsigned short* aAl  = aAh + 3584;                    //  7168 B
    float*          biasL= (float*)(aAl + 3584);          //  2048 B (total 80 KB)
    float*          fpw  = (float*)aAh;                   // overlay after frag loads

    const int blk = blockIdx.x;
    const int b   = blk & (NB - 1);
    const int d   = blk >> 7;
    const int t   = threadIdx.x;
    const int l   = t & 63;
    const int w   = t >> 6;                               // 0..6

    // stage W hi/lo (coalesced), bias
    for (int i = t; i < 2048; i += 448) ((float4*)WBh)[i] = ((const float4*)WBh_g)[d * 2048 + i];
    for (int i = t; i < 2048; i += 448) ((float4*)WBl)[i] = ((const float4*)WBl_g)[d * 2048 + i];
    for (int i = t; i < NU; i += 448)   biasL[i] = b_output[d * NU + i];

    // stage attr -> bf16 hi/lo in A-fragment layout (112 rows x 32 k)
    const float* A = attrAll + ((size_t)b * (ND + 1) + d) * (NA * KF);
    for (int i = t; i < 3584; i += 448) {
        const int gr = i >> 5, k = i & 31;
        const float v = (gr < NA) ? A[gr * KF + k] : 0.f;
        const unsigned short hi = f2bf(v);
        const unsigned short lo = f2bf(v - bf2f(hi));
        const int dst = ((gr >> 4) * 4 + (k >> 3)) * 128 + (gr & 15) * 8 + (k & 7);
        aAh[dst] = hi;
        aAl[dst] = lo;
    }
    __syncthreads();

    // A-fragments for this wave's row-tile
    const int aoff = (w * 4 + (l >> 4)) * 128 + (l & 15) * 8;
    const s16x8 ah = *(const s16x8*)&aAh[aoff];
    const s16x8 al = *(const s16x8*)&aAl[aoff];
    __syncthreads();   // aAh/aAl dead; fpw may overwrite after sweeps

    const int laneoff = (l >> 4) * 128 + (l & 15) * 8;

    // ---- sweep A: row max, hi-only MFMA (no exp) ---------------------------
    float m[4] = {-1e30f, -1e30f, -1e30f, -1e30f};
#pragma unroll 2
    for (int tt = 0; tt < 32; ++tt) {
        const s16x8 bh = *(const s16x8*)&WBh[tt * 512 + laneoff];
        f32x4 c = {0.f, 0.f, 0.f, 0.f};
        c = __builtin_amdgcn_mfma_f32_16x16x32_bf16(ah, bh, c, 0, 0, 0);
        const float bias = biasL[tt * 16 + (l & 15)];
#pragma unroll
        for (int r = 0; r < 4; ++r) m[r] = fmaxf(m[r], c[r] + bias);
    }
#pragma unroll
    for (int off = 1; off <= 8; off <<= 1)
#pragma unroll
        for (int r = 0; r < 4; ++r) m[r] = fmaxf(m[r], __shfl_xor(m[r], off, 64));

    // ---- sweep B: e = exp(c-m), pack to bf16 regs, accumulate s ------------
    unsigned int eP[64];
    float s[4] = {0.f, 0.f, 0.f, 0.f};
#pragma unroll
    for (int tt = 0; tt < 32; ++tt) {
        const s16x8 bh = *(const s16x8*)&WBh[tt * 512 + laneoff];
        const s16x8 bl = *(const s16x8*)&WBl[tt * 512 + laneoff];
        f32x4 c = {0.f, 0.f, 0.f, 0.f};
        c = __builtin_amdgcn_mfma_f32_16x16x32_bf16(ah, bh, c, 0, 0, 0);
        c = __builtin_amdgcn_mfma_f32_16x16x32_bf16(ah, bl, c, 0, 0, 0);
        c = __builtin_amdgcn_mfma_f32_16x16x32_bf16(al, bh, c, 0, 0, 0);
        const float bias = biasL[tt * 16 + (l & 15)];
        const float e0 = __expf(c[0] + bias - m[0]);
        const float e1 = __expf(c[1] + bias - m[1]);
        const float e2 = __expf(c[2] + bias - m[2]);
        const float e3 = __expf(c[3] + bias - m[3]);
        s[0] += e0; s[1] += e1; s[2] += e2; s[3] += e3;
        eP[tt * 2]     = pack_bf16(e0, e1);
        eP[tt * 2 + 1] = pack_bf16(e2, e3);
    }
#pragma unroll
    for (int off = 1; off <= 8; off <<= 1)
#pragma unroll
        for (int r = 0; r < 4; ++r) s[r] += __shfl_xor(s[r], off, 64);

    float inv[4];
#pragma unroll
    for (int r = 0; r < 4; ++r) {
        const int grow = w * 16 + (l >> 4) * 4 + r;
        inv[r] = (grow < NA) ? 1.f / s[r] : 0.f;      // mask pad rows
    }

    // ---- sweep C: fp accumulation from registers (no MFMA/LDS/exp) ---------
#pragma unroll
    for (int tt = 0; tt < 32; ++tt) {
        const unsigned int p01 = eP[tt * 2];
        const unsigned int p23 = eP[tt * 2 + 1];
        float f = __uint_as_float(p01 << 16)          * inv[0]
                + __uint_as_float(p01 & 0xffff0000u)  * inv[1]
                + __uint_as_float(p23 << 16)          * inv[2]
                + __uint_as_float(p23 & 0xffff0000u)  * inv[3];
        f += __shfl_xor(f, 16, 64);
        f += __shfl_xor(f, 32, 64);
        if (l < 16) fpw[w * NU + tt * 16 + l] = f;
    }
    __syncthreads();

    for (int u = t; u < NU; u += 448) {
        float sacc = 0.f;
#pragma unroll
        for (int ww = 0; ww < 7; ++ww) sacc += fpw[ww * NU + u];
        fpPart[((size_t)d * NB + b) * NU + u] = sacc;
    }
}

// ---------------------------------------------------------------------------
// Phase 2c: out[b][u] = sum_d fpPart[d][b][u]
// ---------------------------------------------------------------------------
__global__ __launch_bounds__(512) void p2c_out(const float* __restrict__ fpPart,
                                               float* __restrict__ out)
{
    const int b = blockIdx.x, t = threadIdx.x;
    float s = 0.f;
#pragma unroll
    for (int d = 0; d <= ND; ++d) s += fpPart[((size_t)d * NB + b) * NU + t];
    out[(size_t)b * NU + t] = s;
}

// ---------------------------------------------------------------------------
extern "C" void kernel_launch(void* const* d_in, const int* in_sizes, int n_in,
                              void* d_out, int out_size, void* d_ws, size_t ws_size,
                              hipStream_t stream) {
    (void)in_sizes; (void)n_in; (void)out_size; (void)ws_size;
    const float* x        = (const float*)d_in[0];
    const float* W_inner  = (const float*)d_in[1];
    const float* b_inner  = (const float*)d_in[2];
    const float* W_output = (const float*)d_in[3];
    const float* b_output = (const float*)d_in[4];
    float* out = (float*)d_out;

    float* S0      = (float*)d_ws;
    float* bonds   = S0 + SZ_S0;
    float* attrAll = bonds + SZ_BONDS;
    float* fpPart  = bonds;                       // overlay: bonds dead after p2a
    unsigned short* WBh = (unsigned short*)(attrAll + (size_t)NB * (ND + 1) * NA * KF);
    unsigned short* WBl = WBh + 65536;            // 256 KB after attrAll

    p1_reduce<<<NB * NA, 256, 0, stream>>>(x, S0, attrAll, bonds);
    p2a_recur<<<NB * 2 + 16, 256, 0, stream>>>(S0, bonds, W_inner, b_inner, attrAll,
                                               W_output, WBh, WBl);

    const size_t smemB = 81920;                   // 80 KB
    hipFuncSetAttribute(reinterpret_cast<const void*>(p2b_mfma),
                        hipFuncAttributeMaxDynamicSharedMemorySize, (int)smemB);
    p2b_mfma<<<NB * (ND + 1), 448, smemB, stream>>>(attrAll, WBh, WBl, b_output, fpPart);
    p2c_out<<<NB, 512, 0, stream>>>(fpPart, out);
}